// Round 2
// 442.176 us; speedup vs baseline: 1.0015x; 1.0015x over previous
//
#include <hip/hip_runtime.h>

// y[b,t,:] = x[b,t+1,:] - x[b,t,:]  for t < L-1
// y[b,L-1,:] = x[b,L-1,:] - x[b,L-2,:]
// B=16, L=8192, F=512, fp32.
//
// Register-chained: each thread owns one float4 column (f4) for TSTEP=8
// consecutive timesteps. 9 loads + 8 stores per thread instead of 16+8
// (old kernel read every x element twice, relying on cross-XCD L3 to absorb
// the second fetch). All reuse is in-register. Stores are nontemporal:
// y is write-once, keep it out of L2.
//
// Uses a native clang vector type (f32x4) — __builtin_nontemporal_store
// rejects HIP's float4 class type.

typedef float f32x4 __attribute__((ext_vector_type(4)));

#define B_   16
#define L_   8192
#define F_   512
#define F4_  (F_ / 4)              // 128 float4 per timestep
#define LF4_ (L_ * F4_)            // float4 per batch = 2^20
#define TSTEP 8                    // timesteps per thread
#define TBLK  (2 * TSTEP)          // timesteps per 256-thread block = 16
#define BLOCKS_PER_BATCH (L_ / TBLK)   // 512

__global__ __launch_bounds__(256) void diff1d_kernel(
    const f32x4* __restrict__ x, f32x4* __restrict__ y) {
    // blockIdx.x = b * BLOCKS_PER_BATCH + tb
    int bt = blockIdx.x;
    int b  = bt >> 9;                        // / BLOCKS_PER_BATCH (=512)
    int tb = bt & (BLOCKS_PER_BATCH - 1);

    int f4   = threadIdx.x & (F4_ - 1);      // column within timestep (0..127)
    int half = threadIdx.x >> 7;             // 0 or 1 (wave-uniform)
    int t0   = tb * TBLK + half * TSTEP;     // first timestep this thread owns

    const f32x4* xp = x + (size_t)b * LF4_ + (size_t)t0 * F4_ + f4;
    f32x4*       yp = y + (size_t)b * LF4_ + (size_t)t0 * F4_ + f4;

    // Load the 8 owned timesteps + 1 lookahead (skipped only for the very
    // last tile of each batch, where t0 + TSTEP == L_; branch is uniform).
    f32x4 v[TSTEP + 1];
#pragma unroll
    for (int k = 0; k < TSTEP; ++k)
        v[k] = xp[k * F4_];
    if (t0 + TSTEP < L_)
        v[TSTEP] = xp[TSTEP * F4_];

#pragma unroll
    for (int k = 0; k < TSTEP; ++k) {
        f32x4 d;
        if (t0 + k < L_ - 1) {
            d = v[k + 1] - v[k];             // normal forward diff
        } else {
            // t == L-1 (only k == TSTEP-1 in the last tile): repeat last diff
            d = v[k] - v[k - 1];
        }
        __builtin_nontemporal_store(d, &yp[k * F4_]);
    }
}

extern "C" void kernel_launch(void* const* d_in, const int* in_sizes, int n_in,
                              void* d_out, int out_size, void* d_ws, size_t ws_size,
                              hipStream_t stream) {
    const f32x4* x = (const f32x4*)d_in[0];
    f32x4* y = (f32x4*)d_out;
    (void)in_sizes; (void)n_in; (void)out_size; (void)d_ws; (void)ws_size;

    int grid  = B_ * BLOCKS_PER_BATCH;   // 16 * 512 = 8192 blocks
    int block = 256;
    diff1d_kernel<<<grid, block, 0, stream>>>(x, y);
}

// Round 3
// 426.207 us; speedup vs baseline: 1.0391x; 1.0375x over previous
//
#include <hip/hip_runtime.h>

// y[b,t,:] = x[b,t+1,:] - x[b,t,:]  for t < L-1
// y[b,L-1,:] = x[b,L-1,:] - x[b,L-2,:]
// B=16, L=8192, F=512, fp32.
//
// Register-chained: each thread owns one float4 column for TSTEP=8
// consecutive timesteps (9 loads + 8 stores, 1.125x read redundancy).
//
// Round-2 post-mortem: VGPR_Count=24 proved the compiler rolled the 9
// independent loads back into a dependent load->sub->store chain (only ~2
// vectors live), collapsing per-wave MLP and leaving us latency-bound at
// ~3.3 TB/s while fills on the same run hit 6.6 TB/s.
// Fix: __builtin_amdgcn_sched_barrier(0) between the load phase and the
// compute/store phase — forces all 9 loads issued (and live) before any
// compute. Expect VGPR >= 40.
// NT stores reverted (proven neutral round 0 vs 2); regular stores let L2
// aggregate the write stream.

typedef float f32x4 __attribute__((ext_vector_type(4)));

#define B_   16
#define L_   8192
#define F4_  128                    // float4 per timestep
#define LF4_ (L_ * F4_)             // float4 per batch = 2^20
#define TSTEP 8
#define TBLK  (2 * TSTEP)           // timesteps per 256-thread block
#define BLOCKS_PER_BATCH (L_ / TBLK)   // 512

__global__ __launch_bounds__(256) void diff1d_kernel(
    const f32x4* __restrict__ x, f32x4* __restrict__ y) {
    int bt = blockIdx.x;
    int b  = bt >> 9;                        // / BLOCKS_PER_BATCH
    int tb = bt & (BLOCKS_PER_BATCH - 1);

    int f4   = threadIdx.x & (F4_ - 1);      // 0..127
    int half = threadIdx.x >> 7;             // 0 or 1 (wave-uniform)
    int t0   = tb * TBLK + half * TSTEP;

    const f32x4* xp = x + ((size_t)b << 20) + (size_t)t0 * F4_ + f4;
    f32x4*       yp = y + ((size_t)b << 20) + (size_t)t0 * F4_ + f4;

    // ---- load phase: 9 independent loads, all issued before any compute ----
    f32x4 v[TSTEP + 1];
#pragma unroll
    for (int k = 0; k < TSTEP; ++k)
        v[k] = xp[k * F4_];
    if (t0 + TSTEP < L_)                     // uniform branch; last tile skips
        v[TSTEP] = xp[TSTEP * F4_];

    // Hard scheduling fence: nothing below may be hoisted above, no load may
    // sink below. Forces all 9 vectors live -> MLP of 9 per wave.
    __builtin_amdgcn_sched_barrier(0);

    // ---- compute/store phase ----
#pragma unroll
    for (int k = 0; k < TSTEP; ++k) {
        f32x4 d;
        if (t0 + k < L_ - 1) {
            d = v[k + 1] - v[k];             // forward diff
        } else {
            d = v[k] - v[k - 1];             // t == L-1: repeat last diff
        }
        yp[k * F4_] = d;
    }
}

extern "C" void kernel_launch(void* const* d_in, const int* in_sizes, int n_in,
                              void* d_out, int out_size, void* d_ws, size_t ws_size,
                              hipStream_t stream) {
    const f32x4* x = (const f32x4*)d_in[0];
    f32x4* y = (f32x4*)d_out;
    (void)in_sizes; (void)n_in; (void)out_size; (void)d_ws; (void)ws_size;

    int grid  = B_ * BLOCKS_PER_BATCH;   // 8192 blocks
    int block = 256;
    diff1d_kernel<<<grid, block, 0, stream>>>(x, y);
}